// Round 1
// baseline (212.615 us; speedup 1.0000x reference)
//
#include <hip/hip_runtime.h>

#define IN_CH 256
#define IMG_H 56
#define IMG_W 56
#define QW (IMG_W / 4)   // 14 float4-quads per row

// out[b,c] = conv3x3(x[b,c], w[2c]) + conv3x3(x[b,c^4], w[2(c^4)+1])
// One block per (pair p, batch b); pair p -> channels c0 (bit2==0) and c1=c0^4.
__global__ __launch_bounds__(256) void dwconv_butterfly(
    const float* __restrict__ x, const float* __restrict__ wgt,
    float* __restrict__ out)
{
    const int p  = blockIdx.x;           // 0..127
    const int b  = blockIdx.y;           // 0..31
    const int c0 = ((p >> 2) << 3) | (p & 3);  // bit2 == 0
    const int c1 = c0 ^ 4;

    const size_t chan_elems = (size_t)IMG_H * IMG_W;
    const float* x0 = x + ((size_t)b * IN_CH + c0) * chan_elems;
    const float* x1 = x + ((size_t)b * IN_CH + c1) * chan_elems;
    float* o0 = out + ((size_t)b * IN_CH + c0) * chan_elems;
    float* o1 = out + ((size_t)b * IN_CH + c1) * chan_elems;

    // Filters (wave-uniform addresses -> scalar loads):
    //   o0 <- wa * x0 + wb * x1   where wa = w[2*c0],   wb = w[2*c1+1]
    //   o1 <- wc * x1 + wd * x0   where wc = w[2*c1],   wd = w[2*c0+1]
    float wa[9], wb[9], wc[9], wd[9];
    {
        const float* pa = wgt + (size_t)(2 * c0) * 9;
        const float* pb = wgt + (size_t)(2 * c1 + 1) * 9;
        const float* pc = wgt + (size_t)(2 * c1) * 9;
        const float* pd = wgt + (size_t)(2 * c0 + 1) * 9;
#pragma unroll
        for (int i = 0; i < 9; ++i) {
            wa[i] = pa[i]; wb[i] = pb[i]; wc[i] = pc[i]; wd[i] = pd[i];
        }
    }

    for (int idx = threadIdx.x; idx < IMG_H * QW; idx += 256) {
        const int h  = idx / QW;
        const int j  = idx - h * QW;
        const int w0 = j * 4;

        float acc0[4] = {0.f, 0.f, 0.f, 0.f};
        float acc1[4] = {0.f, 0.f, 0.f, 0.f};

#pragma unroll
        for (int kh = 0; kh < 3; ++kh) {
            const int hh = h + kh - 1;
            float r0[6], r1[6];
            if (hh >= 0 && hh < IMG_H) {
                const float* row0 = x0 + hh * IMG_W + w0;
                const float* row1 = x1 + hh * IMG_W + w0;
                const float4 v0 = *(const float4*)row0;   // 16B aligned: w0%4==0, row stride 224B
                const float4 v1 = *(const float4*)row1;
                r0[1] = v0.x; r0[2] = v0.y; r0[3] = v0.z; r0[4] = v0.w;
                r1[1] = v1.x; r1[2] = v1.y; r1[3] = v1.z; r1[4] = v1.w;
                r0[0] = (w0 > 0)          ? row0[-1] : 0.f;
                r1[0] = (w0 > 0)          ? row1[-1] : 0.f;
                r0[5] = (w0 + 4 < IMG_W)  ? row0[4]  : 0.f;
                r1[5] = (w0 + 4 < IMG_W)  ? row1[4]  : 0.f;
            } else {
#pragma unroll
                for (int i = 0; i < 6; ++i) { r0[i] = 0.f; r1[i] = 0.f; }
            }
#pragma unroll
            for (int kw = 0; kw < 3; ++kw) {
                const float fa = wa[kh * 3 + kw], fb = wb[kh * 3 + kw];
                const float fc = wc[kh * 3 + kw], fd = wd[kh * 3 + kw];
#pragma unroll
                for (int i = 0; i < 4; ++i) {
                    acc0[i] += r0[i + kw] * fa + r1[i + kw] * fb;
                    acc1[i] += r1[i + kw] * fc + r0[i + kw] * fd;
                }
            }
        }

        float4 s0 = make_float4(acc0[0], acc0[1], acc0[2], acc0[3]);
        float4 s1 = make_float4(acc1[0], acc1[1], acc1[2], acc1[3]);
        *(float4*)(o0 + h * IMG_W + w0) = s0;
        *(float4*)(o1 + h * IMG_W + w0) = s1;
    }
}

extern "C" void kernel_launch(void* const* d_in, const int* in_sizes, int n_in,
                              void* d_out, int out_size, void* d_ws, size_t ws_size,
                              hipStream_t stream) {
    const float* x = (const float*)d_in[0];   // (32, 256, 56, 56) fp32
    const float* w = (const float*)d_in[1];   // (512, 1, 3, 3)   fp32
    float* out = (float*)d_out;               // (32, 256, 56, 56) fp32

    dim3 grid(IN_CH / 2, 32);   // 128 channel-pairs x 32 batch
    dim3 block(256);
    dwconv_butterfly<<<grid, block, 0, stream>>>(x, w, out);
}

// Round 2
// 182.204 us; speedup vs baseline: 1.1669x; 1.1669x over previous
//
#include <hip/hip_runtime.h>

#define IN_CH 256
#define IMG_H 56
#define IMG_W 56
#define LDS_W 60                 // row stride in floats: 240B -> 16B-aligned rows, !=0 mod 32 banks
#define LDS_H 58                 // 56 rows + top/bottom zero halo
#define CH_ELEMS (LDS_W * LDS_H) // 3480 floats per channel

// out[b,c]   = conv3x3(x[b,c], w[2c])     + conv3x3(x[b,c^4], w[2(c^4)+1])
// out[b,c^4] = conv3x3(x[b,c^4], w[2(c^4)]) + conv3x3(x[b,c],  w[2c+1])
// One block per (pair p, batch b); pair p -> channels c0 (bit2==0) and c1=c0^4.
__global__ __launch_bounds__(256) void dwconv_butterfly(
    const float* __restrict__ x, const float* __restrict__ wgt,
    float* __restrict__ out)
{
    __shared__ float lds[2 * CH_ELEMS];   // 27840 B

    const int tid = threadIdx.x;
    const int p   = blockIdx.x;           // 0..127
    const int b   = blockIdx.y;           // 0..31
    const int c0  = ((p >> 2) << 3) | (p & 3);  // bit2 == 0
    const int c1  = c0 ^ 4;

    const size_t chan = (size_t)IMG_H * IMG_W;
    const float* x0 = x + ((size_t)b * IN_CH + c0) * chan;
    const float* x1 = x + ((size_t)b * IN_CH + c1) * chan;
    float* o0 = out + ((size_t)b * IN_CH + c0) * chan;
    float* o1 = out + ((size_t)b * IN_CH + c1) * chan;

    // ---- Phase 1a: issue all global loads (independent -> full MLP) ----
    // 2*784 = 1568 float4 chunks, ch-major row-major. 6 per thread + tail for tid<32.
    float4 v[6];
    int    ofs[6];
#pragma unroll
    for (int k = 0; k < 6; ++k) {
        const int q    = tid + 256 * k;          // < 1536 always
        const int ch   = (q >= 784) ? 1 : 0;
        const int rem  = q - ch * 784;
        const int row  = rem / 14;
        const int colq = rem - row * 14;
        const float* src = (ch ? x1 : x0) + row * IMG_W + colq * 4;
        v[k]   = *(const float4*)src;            // 16B aligned
        ofs[k] = ch * CH_ELEMS + (row + 1) * LDS_W + colq * 4 + 1;
    }
    float4 v6; int ofs6 = 0; bool has6 = (tid < 32);
    if (has6) {
        const int q    = tid + 1536;             // 1536..1567, ch==1
        const int rem  = q - 784;
        const int row  = rem / 14;
        const int colq = rem - row * 14;
        v6   = *(const float4*)(x1 + row * IMG_W + colq * 4);
        ofs6 = CH_ELEMS + (row + 1) * LDS_W + colq * 4 + 1;
    }

    // ---- Phase 1b: zero the halo cells (disjoint from interior) ----
    // Per channel: rows {0,57} cols 0..57  (116 cells), rows 1..56 cols {0,57} (112 cells) = 228.
    for (int i = tid; i < 456; i += 256) {
        const int ch = i / 228;
        const int r  = i - ch * 228;
        int row, col;
        if (r < 116) { row = (r / 58) * 57; col = r % 58; }
        else         { const int rr = r - 116; row = 1 + (rr >> 1); col = (rr & 1) * 57; }
        lds[ch * CH_ELEMS + row * LDS_W + col] = 0.f;
    }

    // ---- Phase 1c: commit loaded values to LDS interior ----
#pragma unroll
    for (int k = 0; k < 6; ++k) {
        float* d = &lds[ofs[k]];
        d[0] = v[k].x; d[1] = v[k].y; d[2] = v[k].z; d[3] = v[k].w;
    }
    if (has6) {
        float* d = &lds[ofs6];
        d[0] = v6.x; d[1] = v6.y; d[2] = v6.z; d[3] = v6.w;
    }

    __syncthreads();

    // ---- Phase 2: weights (wave-uniform -> scalar loads) ----
    float wa[9], wb[9], wc[9], wd[9];
    {
        const float* pa = wgt + (size_t)(2 * c0) * 9;
        const float* pb = wgt + (size_t)(2 * c1 + 1) * 9;
        const float* pc = wgt + (size_t)(2 * c1) * 9;
        const float* pd = wgt + (size_t)(2 * c0 + 1) * 9;
#pragma unroll
        for (int i = 0; i < 9; ++i) {
            wa[i] = pa[i]; wb[i] = pb[i]; wc[i] = pc[i]; wd[i] = pd[i];
        }
    }

    // ---- Phase 3: compute from LDS ----
    auto compute_quad = [&](int idx) {
        const int h  = idx / 14;
        const int w0 = (idx - h * 14) * 4;
        float acc0[4] = {0.f, 0.f, 0.f, 0.f};
        float acc1[4] = {0.f, 0.f, 0.f, 0.f};
#pragma unroll
        for (int kh = 0; kh < 3; ++kh) {
            // lds col c holds x col c-1; need x cols w0-1..w0+4 -> lds cols w0..w0+5
            const float* p0 = &lds[(h + kh) * LDS_W + w0];             // 16B aligned
            const float* p1 = p0 + CH_ELEMS;
            const float4 a0 = *(const float4*)p0;
            const float2 b0 = *(const float2*)(p0 + 4);
            const float4 a1 = *(const float4*)p1;
            const float2 b1 = *(const float2*)(p1 + 4);
            const float r0[6] = {a0.x, a0.y, a0.z, a0.w, b0.x, b0.y};
            const float r1[6] = {a1.x, a1.y, a1.z, a1.w, b1.x, b1.y};
#pragma unroll
            for (int kw = 0; kw < 3; ++kw) {
                const float fa = wa[kh * 3 + kw], fb = wb[kh * 3 + kw];
                const float fc = wc[kh * 3 + kw], fd = wd[kh * 3 + kw];
#pragma unroll
                for (int i = 0; i < 4; ++i) {
                    acc0[i] += r0[i + kw] * fa + r1[i + kw] * fb;
                    acc1[i] += r1[i + kw] * fc + r0[i + kw] * fd;
                }
            }
        }
        *(float4*)(o0 + h * IMG_W + w0) = make_float4(acc0[0], acc0[1], acc0[2], acc0[3]);
        *(float4*)(o1 + h * IMG_W + w0) = make_float4(acc1[0], acc1[1], acc1[2], acc1[3]);
    };

    // 784 quads: 3 uniform per thread + tail for tid<16
#pragma unroll
    for (int k = 0; k < 3; ++k) compute_quad(tid + 256 * k);
    if (tid < 16) compute_quad(768 + tid);
}

extern "C" void kernel_launch(void* const* d_in, const int* in_sizes, int n_in,
                              void* d_out, int out_size, void* d_ws, size_t ws_size,
                              hipStream_t stream) {
    const float* x = (const float*)d_in[0];   // (32, 256, 56, 56) fp32
    const float* w = (const float*)d_in[1];   // (512, 1, 3, 3)   fp32
    float* out = (float*)d_out;               // (32, 256, 56, 56) fp32

    dim3 grid(IN_CH / 2, 32);   // 128 channel-pairs x 32 batch
    dim3 block(256);
    dwconv_butterfly<<<grid, block, 0, stream>>>(x, w, out);
}